// Round 3
// baseline (856.316 us; speedup 1.0000x reference)
//
#include <hip/hip_runtime.h>
#include <math.h>

#define B    64
#define T    4096
#define DENC 512
#define DDEC 512
#define DATT 256

typedef __attribute__((ext_vector_type(8))) short          short8;
typedef __attribute__((ext_vector_type(8))) unsigned short ushort8v;
typedef __attribute__((ext_vector_type(4))) float          f32x4;

// float -> bf16, round-to-nearest-even (used only in tiny one-shot kernels)
__device__ __forceinline__ unsigned short f2bf(float f) {
    union { float f; unsigned u; } v; v.f = f;
    return (unsigned short)((v.u + 0x7fffu + ((v.u >> 16) & 1u)) >> 16);
}

// two f32 -> packed bf16 pair (round-half-up): 2 adds + 1 v_perm_b32.
// out = [bf16(b) : bf16(a)]  (a in low half)
__device__ __forceinline__ unsigned pk2bf(float a, float b) {
    unsigned ua = __float_as_uint(a) + 0x8000u;
    unsigned ub = __float_as_uint(b) + 0x8000u;
    return __builtin_amdgcn_perm(ub, ua, 0x07060302u);
}

__device__ __forceinline__ float bf2f(unsigned short u) {
    return __uint_as_float((unsigned)u << 16);
}

// tanh via exp pipe
__device__ __forceinline__ float tanh_fast(float x) {
    float e = __expf(2.0f * x);
    return 1.0f - 2.0f / (e + 1.0f);
}

// ---------------------------------------------------------------------------
// K0: Wk_w f32 [DATT][DENC] -> bf16 (RNE) in workspace, same layout.
// ---------------------------------------------------------------------------
__global__ __launch_bounds__(256) void k_wkconv(const float* __restrict__ Wk_w,
                                                unsigned short* __restrict__ WkB) {
    int i = (blockIdx.x * 256 + threadIdx.x) * 4;
    float4 v = *(const float4*)(Wk_w + i);
    ushort4 o;
    o.x = f2bf(v.x); o.y = f2bf(v.y); o.z = f2bf(v.z); o.w = f2bf(v.w);
    *(ushort4*)(WkB + i) = o;
}

// ---------------------------------------------------------------------------
// K1: qq[b,a] = dot(Wq_w[a,:], h_dec[b,:]) + Wq_b[a] + Wk_b[a]
// ---------------------------------------------------------------------------
__global__ __launch_bounds__(256) void k_qproj(const float* __restrict__ h_dec,
                                               const float* __restrict__ Wq_w,
                                               const float* __restrict__ Wq_b,
                                               const float* __restrict__ Wk_b,
                                               float* __restrict__ qq) {
    __shared__ float sh[DDEC];
    const int b = blockIdx.x;
    const int tid = threadIdx.x;
    ((float2*)sh)[tid] = ((const float2*)(h_dec + (size_t)b * DDEC))[tid];
    __syncthreads();
    const int a = tid;
    const float4* wr  = (const float4*)(Wq_w + (size_t)a * DDEC);
    const float4* shv = (const float4*)sh;
    float acc = 0.f;
#pragma unroll 4
    for (int i = 0; i < DDEC / 4; ++i) {
        float4 wv = wr[i];
        float4 hv = shv[i];
        acc += wv.x * hv.x + wv.y * hv.y + wv.z * hv.z + wv.w * hv.w;
    }
    qq[b * DATT + a] = acc + Wq_b[a] + Wk_b[a];
}

// ---------------------------------------------------------------------------
// K2: fused k-projection + additive score via bf16 MFMA.
//   Block tile: 128 t x 256 a, BK=32.  4 waves in 2x2 grid, each wave
//   64t x 128a = 4x8 tiles of mfma_f32_16x16x32_bf16.
//   A staged f32 -> bf16 via pk2bf (3 VALU per pair) + ds_write_b128; the
//   converted tile is ALSO written to global hB (bf16 h_enc) for k_ctx.
//   B tile staged via async global_load_lds(16B).
//   LDS 16B chunks XOR-swizzled (slot = kchunk ^ ((row>>1)&3)).
// ---------------------------------------------------------------------------
#define BM 128
#define BK 32

__global__ __launch_bounds__(256, 2) void k_score(const float* __restrict__ h_enc,
                                                  const unsigned short* __restrict__ WkB,
                                                  const float* __restrict__ qq,
                                                  const float* __restrict__ v_w,
                                                  const int* __restrict__ mask,
                                                  unsigned short* __restrict__ hB,
                                                  float* __restrict__ scores) {
    __shared__ short As[BM * BK];    // 8 KB
    __shared__ short Bs[DATT * BK];  // 16 KB
    __shared__ float sp[2][BM];

    const int tc   = blockIdx.x;
    const int b    = blockIdx.y;
    const int tid  = threadIdx.x;
    const int wv   = tid >> 6;
    const int lane = tid & 63;
    const int ln15 = lane & 15;
    const int qd   = lane >> 4;
    const int wv_t = wv >> 1;
    const int wv_a = wv & 1;
    const int t0   = tc * BM;

    f32x4 acc[4][8];
#pragma unroll
    for (int i = 0; i < 4; ++i)
#pragma unroll
        for (int j = 0; j < 8; ++j) acc[i][j] = (f32x4){0.f, 0.f, 0.f, 0.f};

    const float* Abase = h_enc + ((size_t)b * T + t0) * DENC;
    unsigned short* hBbase = hB + ((size_t)b * T + t0) * DENC;

    for (int k0 = 0; k0 < DENC; k0 += BK) {
        // ---- B tile: async bf16 global->LDS, 4 chunks of 16B per thread ----
#pragma unroll
        for (int it = 0; it < 4; ++it) {
            int idx = (wv * 4 + it) * 64 + lane;
            int r   = idx >> 2;
            int cc  = (idx & 3) ^ ((r >> 1) & 3);
            const unsigned short* gp = WkB + (size_t)r * DENC + k0 + cc * 8;
            short* lp = &Bs[(wv * 4 + it) * 64 * 8];
            __builtin_amdgcn_global_load_lds(
                (const __attribute__((address_space(1))) unsigned int*)gp,
                (__attribute__((address_space(3))) unsigned int*)lp, 16, 0, 0);
        }
        // ---- A tile: f32 load, packed cvt, ds_write_b128 + global bf16 out --
#pragma unroll
        for (int it = 0; it < 2; ++it) {
            int idx = it * 256 + tid;
            int r   = idx >> 2;
            int cc  = (idx & 3) ^ ((r >> 1) & 3);
            const float* gp = Abase + (size_t)r * DENC + k0 + cc * 8;
            float4 v0 = *(const float4*)gp;
            float4 v1 = *(const float4*)(gp + 4);
            uint4 pk;
            pk.x = pk2bf(v0.x, v0.y);
            pk.y = pk2bf(v0.z, v0.w);
            pk.z = pk2bf(v1.x, v1.y);
            pk.w = pk2bf(v1.z, v1.w);
            *(uint4*)&As[idx * 8] = pk;
            *(uint4*)(hBbase + (size_t)r * DENC + k0 + cc * 8) = pk;
        }
        __syncthreads();

        // ---- fragments + MFMA ----
        short8 af[4], bfr[8];
#pragma unroll
        for (int ti = 0; ti < 4; ++ti) {
            int r = wv_t * 64 + ti * 16 + ln15;
            int s = qd ^ ((r >> 1) & 3);
            af[ti] = *(const short8*)&As[r * 32 + s * 8];
        }
#pragma unroll
        for (int tj = 0; tj < 8; ++tj) {
            int r = wv_a * 128 + tj * 16 + ln15;
            int s = qd ^ ((r >> 1) & 3);
            bfr[tj] = *(const short8*)&Bs[r * 32 + s * 8];
        }
#pragma unroll
        for (int ti = 0; ti < 4; ++ti)
#pragma unroll
            for (int tj = 0; tj < 8; ++tj)
                acc[ti][tj] = __builtin_amdgcn_mfma_f32_16x16x32_bf16(
                    af[ti], bfr[tj], acc[ti][tj], 0, 0, 0);
        __syncthreads();
    }

    // ---- epilogue: s[t] = sum_a v[a]*tanh(qq[a] + k[t,a]) ----
    float qr[8], vr[8];
#pragma unroll
    for (int tj = 0; tj < 8; ++tj) {
        int a = wv_a * 128 + tj * 16 + ln15;
        qr[tj] = qq[b * DATT + a];
        vr[tj] = v_w[a];
    }
#pragma unroll
    for (int ti = 0; ti < 4; ++ti) {
#pragma unroll
        for (int rg = 0; rg < 4; ++rg) {
            float s = 0.f;
#pragma unroll
            for (int tj = 0; tj < 8; ++tj)
                s += vr[tj] * tanh_fast(qr[tj] + acc[ti][tj][rg]);
            s += __shfl_xor(s, 1, 64);
            s += __shfl_xor(s, 2, 64);
            s += __shfl_xor(s, 4, 64);
            s += __shfl_xor(s, 8, 64);
            if (ln15 == 0)
                sp[wv_a][wv_t * 64 + ti * 16 + qd * 4 + rg] = s;
        }
    }
    __syncthreads();
    if (tid < BM) {
        int t = t0 + tid;
        float s = sp[0][tid] + sp[1][tid];
        bool m = mask[(size_t)b * T + t] != 0;
        scores[(size_t)b * T + t] = m ? s : -1e9f;
    }
}

// ---------------------------------------------------------------------------
// K3: in-place softmax over T per batch row.
// ---------------------------------------------------------------------------
__global__ __launch_bounds__(256) void k_softmax(float* __restrict__ w) {
    const int b = blockIdx.x;
    const int tid = threadIdx.x;
    const int wid = tid >> 6, lane = tid & 63;
    float* row = w + (size_t)b * T;
    __shared__ float red[4];
    __shared__ float bmax_s, bsum_s;

    float x[T / 256];
#pragma unroll
    for (int i = 0; i < T / 256; ++i) x[i] = row[tid + i * 256];

    float lmax = -INFINITY;
#pragma unroll
    for (int i = 0; i < T / 256; ++i) lmax = fmaxf(lmax, x[i]);
#pragma unroll
    for (int off = 32; off >= 1; off >>= 1) lmax = fmaxf(lmax, __shfl_xor(lmax, off, 64));
    if (lane == 0) red[wid] = lmax;
    __syncthreads();
    if (tid == 0) bmax_s = fmaxf(fmaxf(red[0], red[1]), fmaxf(red[2], red[3]));
    __syncthreads();
    const float bmax = bmax_s;

    float lsum = 0.f;
#pragma unroll
    for (int i = 0; i < T / 256; ++i) { x[i] = __expf(x[i] - bmax); lsum += x[i]; }
#pragma unroll
    for (int off = 32; off >= 1; off >>= 1) lsum += __shfl_xor(lsum, off, 64);
    if (lane == 0) red[wid] = lsum;
    __syncthreads();
    if (tid == 0) bsum_s = red[0] + red[1] + red[2] + red[3];
    __syncthreads();
    const float inv = 1.f / bsum_s;
#pragma unroll
    for (int i = 0; i < T / 256; ++i) row[tid + i * 256] = x[i] * inv;
}

// ---------------------------------------------------------------------------
// K4: ctx[b,e] = sum_t w[b,t]*hB[b,t,e] (bf16 h).  Each wave reads one full
// 1 KB row (64 lanes x ushort8) per iter; 4-way t-split across waves;
// LDS combine; 8 atomics/lane into zeroed ctx.
// ---------------------------------------------------------------------------
#define TCH 512
__global__ __launch_bounds__(256) void k_ctx(const unsigned short* __restrict__ hB,
                                             const float* __restrict__ w,
                                             float* __restrict__ ctx) {
    const int b   = blockIdx.y;
    const int t0  = blockIdx.x * TCH;
    const int tid = threadIdx.x;
    const int lane = tid & 63, wv = tid >> 6;
    const int e8 = lane * 8;
    __shared__ float ws[TCH];
    __shared__ float red[3][DENC];

    ((float2*)ws)[tid] = ((const float2*)(w + (size_t)b * T + t0))[tid];
    __syncthreads();

    const unsigned short* hp = hB + ((size_t)(b * T + t0 + wv)) * DENC + e8;
    float a[8];
#pragma unroll
    for (int j = 0; j < 8; ++j) a[j] = 0.f;

#pragma unroll 4
    for (int t = wv; t < TCH; t += 4) {
        float wt = ws[t];
        ushort8v hv = *(const ushort8v*)hp;
        hp += (size_t)4 * DENC;
#pragma unroll
        for (int j = 0; j < 8; ++j)
            a[j] = fmaf(wt, bf2f((unsigned short)hv[j]), a[j]);
    }

    if (wv > 0) {
#pragma unroll
        for (int j = 0; j < 8; ++j) red[wv - 1][e8 + j] = a[j];
    }
    __syncthreads();
    if (wv == 0) {
#pragma unroll
        for (int j = 0; j < 8; ++j) {
            float s = a[j] + red[0][e8 + j] + red[1][e8 + j] + red[2][e8 + j];
            atomicAdd(&ctx[b * DENC + e8 + j], s);
        }
    }
}

// ---------------------------------------------------------------------------
extern "C" void kernel_launch(void* const* d_in, const int* in_sizes, int n_in,
                              void* d_out, int out_size, void* d_ws, size_t ws_size,
                              hipStream_t stream) {
    const float* h_enc = (const float*)d_in[0];
    const float* h_dec = (const float*)d_in[1];
    const float* Wq_w  = (const float*)d_in[2];
    const float* Wq_b  = (const float*)d_in[3];
    const float* Wk_w  = (const float*)d_in[4];
    const float* Wk_b  = (const float*)d_in[5];
    const float* v_w   = (const float*)d_in[6];
    const int*   mask  = (const int*)d_in[7];

    float* out = (float*)d_out;
    float* ctx = out;               // [B, DENC]
    float* wts = out + B * DENC;    // [B, T]

    float*          qq  = (float*)d_ws;                                  // 64 KB
    unsigned short* WkB = (unsigned short*)((char*)d_ws + (64 << 10));   // 256 KB
    unsigned short* hB  = (unsigned short*)((char*)d_ws + (1 << 20));    // 268 MB

    hipMemsetAsync(ctx, 0, (size_t)B * DENC * sizeof(float), stream);

    k_wkconv<<<DATT * DENC / 4 / 256, 256, 0, stream>>>(Wk_w, WkB);
    k_qproj<<<B, 256, 0, stream>>>(h_dec, Wq_w, Wq_b, Wk_b, qq);
    k_score<<<dim3(T / BM, B), 256, 0, stream>>>(h_enc, WkB, qq, v_w, mask, hB, wts);
    k_softmax<<<B, 256, 0, stream>>>(wts);
    k_ctx<<<dim3(T / TCH, B), 256, 0, stream>>>(hB, wts, ctx);
}

// Round 4
// 804.545 us; speedup vs baseline: 1.0643x; 1.0643x over previous
//
#include <hip/hip_runtime.h>
#include <math.h>

#define B    64
#define T    4096
#define DENC 512
#define DDEC 512
#define DATT 256

#define BM   128
#define BK   32
#define NCH  (T / BM)   // 32 t-chunks per batch row

typedef __attribute__((ext_vector_type(8))) short short8;
typedef __attribute__((ext_vector_type(4))) float f32x4;

// float -> bf16, round-to-nearest-even (tiny one-shot kernels only)
__device__ __forceinline__ unsigned short f2bf(float f) {
    union { float f; unsigned u; } v; v.f = f;
    return (unsigned short)((v.u + 0x7fffu + ((v.u >> 16) & 1u)) >> 16);
}

// two f32 -> packed bf16 pair (round-half-up): 2 adds + 1 v_perm_b32
__device__ __forceinline__ unsigned pk2bf(float a, float b) {
    unsigned ua = __float_as_uint(a) + 0x8000u;
    unsigned ub = __float_as_uint(b) + 0x8000u;
    return __builtin_amdgcn_perm(ub, ua, 0x07060302u);
}

__device__ __forceinline__ float tanh_fast(float x) {
    float e = __expf(2.0f * x);
    return 1.0f - 2.0f / (e + 1.0f);
}

// ---------------------------------------------------------------------------
// K0: Wk_w f32 -> bf16 in workspace.
// ---------------------------------------------------------------------------
__global__ __launch_bounds__(256) void k_wkconv(const float* __restrict__ Wk_w,
                                                unsigned short* __restrict__ WkB) {
    int i = (blockIdx.x * 256 + threadIdx.x) * 4;
    float4 v = *(const float4*)(Wk_w + i);
    ushort4 o;
    o.x = f2bf(v.x); o.y = f2bf(v.y); o.z = f2bf(v.z); o.w = f2bf(v.w);
    *(ushort4*)(WkB + i) = o;
}

// ---------------------------------------------------------------------------
// K1: qq[b,a] = dot(Wq_w[a,:], h_dec[b,:]) + Wq_b[a] + Wk_b[a]
// ---------------------------------------------------------------------------
__global__ __launch_bounds__(256) void k_qproj(const float* __restrict__ h_dec,
                                               const float* __restrict__ Wq_w,
                                               const float* __restrict__ Wq_b,
                                               const float* __restrict__ Wk_b,
                                               float* __restrict__ qq) {
    __shared__ float sh[DDEC];
    const int b = blockIdx.x;
    const int tid = threadIdx.x;
    ((float2*)sh)[tid] = ((const float2*)(h_dec + (size_t)b * DDEC))[tid];
    __syncthreads();
    const int a = tid;
    const float4* wr  = (const float4*)(Wq_w + (size_t)a * DDEC);
    const float4* shv = (const float4*)sh;
    float acc = 0.f;
#pragma unroll 4
    for (int i = 0; i < DDEC / 4; ++i) {
        float4 wv = wr[i];
        float4 hv = shv[i];
        acc += wv.x * hv.x + wv.y * hv.y + wv.z * hv.z + wv.w * hv.w;
    }
    qq[b * DATT + a] = acc + Wq_b[a] + Wk_b[a];
}

// ---------------------------------------------------------------------------
// K2 (fused): per (t-chunk, b) block:
//   phase 1: bf16 MFMA score GEMM (identical to proven R2 structure, no hB)
//   phase 2: masked scores -> global; block-local online-softmax partial
//            m = max s, p_t = exp(s_t-m), l = sum p; (m,l) -> partials
//   phase 3: ctx_part[e] = sum_t p_t * h_enc[t][e], re-reading own tile
//            (L3-resident) -> part_ctx
// ---------------------------------------------------------------------------
__global__ __launch_bounds__(256, 2) void k_fused(const float* __restrict__ h_enc,
                                                  const unsigned short* __restrict__ WkB,
                                                  const float* __restrict__ qq,
                                                  const float* __restrict__ v_w,
                                                  const int* __restrict__ mask,
                                                  float* __restrict__ scores,
                                                  float* __restrict__ part_m,
                                                  float* __restrict__ part_l,
                                                  float* __restrict__ part_ctx) {
    __shared__ short As[BM * BK];    // 8 KB
    __shared__ short Bs[DATT * BK];  // 16 KB
    __shared__ float sp[2][BM];
    __shared__ float ps[BM];
    __shared__ float red_a[4], red_b[4];

    const int tc   = blockIdx.x;
    const int b    = blockIdx.y;
    const int tid  = threadIdx.x;
    const int wv   = tid >> 6;
    const int lane = tid & 63;
    const int ln15 = lane & 15;
    const int qd   = lane >> 4;
    const int wv_t = wv >> 1;
    const int wv_a = wv & 1;
    const int t0   = tc * BM;

    f32x4 acc[4][8];
#pragma unroll
    for (int i = 0; i < 4; ++i)
#pragma unroll
        for (int j = 0; j < 8; ++j) acc[i][j] = (f32x4){0.f, 0.f, 0.f, 0.f};

    const float* Abase = h_enc + ((size_t)b * T + t0) * DENC;

    for (int k0 = 0; k0 < DENC; k0 += BK) {
        // ---- B tile: async bf16 global->LDS, 4 x 16B chunks per thread ----
#pragma unroll
        for (int it = 0; it < 4; ++it) {
            int idx = (wv * 4 + it) * 64 + lane;
            int r   = idx >> 2;
            int cc  = (idx & 3) ^ ((r >> 1) & 3);
            const unsigned short* gp = WkB + (size_t)r * DENC + k0 + cc * 8;
            short* lp = &Bs[(wv * 4 + it) * 64 * 8];
            __builtin_amdgcn_global_load_lds(
                (const __attribute__((address_space(1))) unsigned int*)gp,
                (__attribute__((address_space(3))) unsigned int*)lp, 16, 0, 0);
        }
        // ---- A tile: f32 load, packed cvt, ds_write_b128 (swizzled) ----
#pragma unroll
        for (int it = 0; it < 2; ++it) {
            int idx = it * 256 + tid;
            int r   = idx >> 2;
            int cc  = (idx & 3) ^ ((r >> 1) & 3);
            const float* gp = Abase + (size_t)r * DENC + k0 + cc * 8;
            float4 v0 = *(const float4*)gp;
            float4 v1 = *(const float4*)(gp + 4);
            uint4 pk;
            pk.x = pk2bf(v0.x, v0.y);
            pk.y = pk2bf(v0.z, v0.w);
            pk.z = pk2bf(v1.x, v1.y);
            pk.w = pk2bf(v1.z, v1.w);
            *(uint4*)&As[idx * 8] = pk;
        }
        __syncthreads();

        // ---- fragments + MFMA ----
        short8 af[4], bfr[8];
#pragma unroll
        for (int ti = 0; ti < 4; ++ti) {
            int r = wv_t * 64 + ti * 16 + ln15;
            int s = qd ^ ((r >> 1) & 3);
            af[ti] = *(const short8*)&As[r * 32 + s * 8];
        }
#pragma unroll
        for (int tj = 0; tj < 8; ++tj) {
            int r = wv_a * 128 + tj * 16 + ln15;
            int s = qd ^ ((r >> 1) & 3);
            bfr[tj] = *(const short8*)&Bs[r * 32 + s * 8];
        }
#pragma unroll
        for (int ti = 0; ti < 4; ++ti)
#pragma unroll
            for (int tj = 0; tj < 8; ++tj)
                acc[ti][tj] = __builtin_amdgcn_mfma_f32_16x16x32_bf16(
                    af[ti], bfr[tj], acc[ti][tj], 0, 0, 0);
        __syncthreads();
    }

    // ---- epilogue: s[t] = sum_a v[a]*tanh(qq[a] + k[t,a]) ----
    float qr[8], vr[8];
#pragma unroll
    for (int tj = 0; tj < 8; ++tj) {
        int a = wv_a * 128 + tj * 16 + ln15;
        qr[tj] = qq[b * DATT + a];
        vr[tj] = v_w[a];
    }
#pragma unroll
    for (int ti = 0; ti < 4; ++ti) {
#pragma unroll
        for (int rg = 0; rg < 4; ++rg) {
            float s = 0.f;
#pragma unroll
            for (int tj = 0; tj < 8; ++tj)
                s += vr[tj] * tanh_fast(qr[tj] + acc[ti][tj][rg]);
            s += __shfl_xor(s, 1, 64);
            s += __shfl_xor(s, 2, 64);
            s += __shfl_xor(s, 4, 64);
            s += __shfl_xor(s, 8, 64);
            if (ln15 == 0)
                sp[wv_a][wv_t * 64 + ti * 16 + qd * 4 + rg] = s;
        }
    }
    __syncthreads();

    // ---- phase 2: masked scores + block-local softmax partial ----
    if (tid < BM) {
        int t = t0 + tid;
        float s = sp[0][tid] + sp[1][tid];
        bool mk = mask[(size_t)b * T + t] != 0;
        s = mk ? s : -1e9f;
        scores[(size_t)b * T + t] = s;
        ps[tid] = s;
    }
    __syncthreads();

    float mv = (tid < BM) ? ps[tid] : -INFINITY;
#pragma unroll
    for (int off = 32; off >= 1; off >>= 1) mv = fmaxf(mv, __shfl_xor(mv, off, 64));
    if (lane == 0) red_a[wv] = mv;
    __syncthreads();
    const float M = fmaxf(fmaxf(red_a[0], red_a[1]), fmaxf(red_a[2], red_a[3]));

    float p = 0.f;
    if (tid < BM) { p = __expf(ps[tid] - M); ps[tid] = p; }
    float ls = p;
#pragma unroll
    for (int off = 32; off >= 1; off >>= 1) ls += __shfl_xor(ls, off, 64);
    if (lane == 0) red_b[wv] = ls;
    __syncthreads();
    if (tid == 0) {
        part_m[b * NCH + tc] = M;
        part_l[b * NCH + tc] = red_b[0] + red_b[1] + red_b[2] + red_b[3];
    }

    // ---- phase 3: ctx_part[e] = sum_t p_t * h_enc[t][e] (tile re-read) ----
    const float2* hp = (const float2*)(Abase) + tid;  // e = 2*tid, 2*tid+1
    float ax = 0.f, ay = 0.f;
#pragma unroll 8
    for (int t = 0; t < BM; ++t) {
        float pt = ps[t];
        float2 hv = hp[(size_t)t * (DENC / 2)];
        ax = fmaf(pt, hv.x, ax);
        ay = fmaf(pt, hv.y, ay);
    }
    float2* pc = (float2*)(part_ctx + ((size_t)(b * NCH + tc)) * DENC) + tid;
    *pc = make_float2(ax, ay);
}

// ---------------------------------------------------------------------------
// K3: per-b combine of NCH partials -> ctx + (M, 1/L)
// ---------------------------------------------------------------------------
__global__ __launch_bounds__(256) void k_combine(const float* __restrict__ part_m,
                                                 const float* __restrict__ part_l,
                                                 const float* __restrict__ part_ctx,
                                                 float* __restrict__ ctx,
                                                 float2* __restrict__ ml) {
    const int b = blockIdx.x;
    const int tid = threadIdx.x;
    __shared__ float sm[NCH], sl[NCH];
    if (tid < NCH) {
        sm[tid] = part_m[b * NCH + tid];
        sl[tid] = part_l[b * NCH + tid];
    }
    __syncthreads();
    float M = -INFINITY;
#pragma unroll
    for (int i = 0; i < NCH; ++i) M = fmaxf(M, sm[i]);

    float L = 0.f, ax = 0.f, ay = 0.f;
    const float2* pc = (const float2*)(part_ctx + (size_t)b * NCH * DENC) + tid;
#pragma unroll 4
    for (int i = 0; i < NCH; ++i) {
        float sc = __expf(sm[i] - M);
        L += sl[i] * sc;
        float2 v = pc[(size_t)i * (DENC / 2)];
        ax = fmaf(sc, v.x, ax);
        ay = fmaf(sc, v.y, ay);
    }
    float inv = 1.f / L;
    ((float2*)(ctx + b * DENC))[tid] = make_float2(ax * inv, ay * inv);
    if (tid == 0) ml[b] = make_float2(M, inv);
}

// ---------------------------------------------------------------------------
// K4: w[b,t] = exp(scores[b,t] - M_b) * invL_b
// ---------------------------------------------------------------------------
__global__ __launch_bounds__(256) void k_w(const float* __restrict__ scores,
                                           const float2* __restrict__ ml,
                                           float* __restrict__ w) {
    const int b = blockIdx.y;
    float2 m = ml[b];
    size_t off = (size_t)b * T + blockIdx.x * 1024 + threadIdx.x * 4;
    float4 s = *(const float4*)(scores + off);
    float4 o;
    o.x = __expf(s.x - m.x) * m.y;
    o.y = __expf(s.y - m.x) * m.y;
    o.z = __expf(s.z - m.x) * m.y;
    o.w = __expf(s.w - m.x) * m.y;
    *(float4*)(w + off) = o;
}

// ---------------------------------------------------------------------------
extern "C" void kernel_launch(void* const* d_in, const int* in_sizes, int n_in,
                              void* d_out, int out_size, void* d_ws, size_t ws_size,
                              hipStream_t stream) {
    const float* h_enc = (const float*)d_in[0];
    const float* h_dec = (const float*)d_in[1];
    const float* Wq_w  = (const float*)d_in[2];
    const float* Wq_b  = (const float*)d_in[3];
    const float* Wk_w  = (const float*)d_in[4];
    const float* Wk_b  = (const float*)d_in[5];
    const float* v_w   = (const float*)d_in[6];
    const int*   mask  = (const int*)d_in[7];

    float* out = (float*)d_out;
    float* ctx = out;               // [B, DENC]
    float* wts = out + B * DENC;    // [B, T]

    char* ws = (char*)d_ws;
    float*          qq       = (float*)ws;                       // 64 KB
    unsigned short* WkB      = (unsigned short*)(ws + (64 << 10));   // 256 KB
    float*          scores   = (float*)(ws + (1 << 20));             // 1 MB
    float*          part_m   = (float*)(ws + (2 << 20));             // 8 KB
    float*          part_l   = (float*)(ws + (2 << 20) + (16 << 10));
    float2*         ml       = (float2*)(ws + (2 << 20) + (32 << 10));
    float*          part_ctx = (float*)(ws + (3 << 20));             // 4 MB

    k_wkconv<<<DATT * DENC / 4 / 256, 256, 0, stream>>>(Wk_w, WkB);
    k_qproj<<<B, 256, 0, stream>>>(h_dec, Wq_w, Wq_b, Wk_b, qq);
    k_fused<<<dim3(NCH, B), 256, 0, stream>>>(h_enc, WkB, qq, v_w, mask,
                                              scores, part_m, part_l, part_ctx);
    k_combine<<<B, 256, 0, stream>>>(part_m, part_l, part_ctx, ctx, ml);
    k_w<<<dim3(T / 1024, B), 256, 0, stream>>>(scores, ml, wts);
}